// Round 4
// baseline (449.568 us; speedup 1.0000x reference)
//
#include <hip/hip_runtime.h>
#include <stdint.h>

// ---------------------------------------------------------------------------
// LSH layer: out[n,s] = sum_d x[n,d] * W[ids[s],d] + bias[ids[s]]
// R6: R4's 8-phase 256-square schedule MINUS the sched_barrier(0) spam.
//     R4 carried ~24 sched_barrier(0) per K-tile (m141: order-pinning =
//     -40%); m201's verified template uses none except the rule-#18 fence
//     right after each lgkmcnt(0). Also removed the XCD swizzle (R5 showed
//     locality remaps regress on this L3-fit working set).
//     Structure (unchanged from R4, twice harness-verified):
//       - BM=BN=256, BK=64, 512 thr = 8 waves (2Mx4N), 128x64 out/wave
//       - staging granularity = K-half (256x32, 2 gload_lds/thread):
//         per tile {A-k0, B-k0, A-k1, B-k1}, double-buffered (128 KiB LDS)
//       - 4 phases/tile, 16 MFMA each; stage 1 half-tile per phase
//       - counted vmcnt(4) at ph1/ph3 (FIFO-verified: retires exactly the
//         half-tiles the next two phases read; never drains to 0 mid-loop)
//       - LDS swizzle [256][32]: phys chunk = logical ^ ((row>>1)&3)
// ---------------------------------------------------------------------------

typedef __bf16 bf16x8 __attribute__((ext_vector_type(8)));
typedef float f32x4 __attribute__((ext_vector_type(4)));

#define BM 256
#define BN 256
#define BK 64
#define KH 32
#define HB 8192  // ushorts per half-buffer: 256*32

__device__ __forceinline__ ushort f2bf(float f) {
  union { float f; uint32_t u; } c; c.f = f;
  uint32_t u = c.u;
  return (ushort)((u + 0x7FFFu + ((u >> 16) & 1u)) >> 16);
}

__global__ __launch_bounds__(256) void prep_kernel(
    const float* __restrict__ x, const float* __restrict__ W,
    const float* __restrict__ bias, const int* __restrict__ ids,
    ushort* __restrict__ Wg, ushort* __restrict__ xb,
    float* __restrict__ biasg, int D, int S) {
  const int t = threadIdx.x;
  const int gblocks = S >> 3;
  if ((int)blockIdx.x < gblocks) {
    const int s0 = blockIdx.x << 3;
    if (t < 8) biasg[s0 + t] = bias[ids[s0 + t]];
#pragma unroll
    for (int r = 0; r < 8; ++r) {
      const int s = s0 + r;
      const int id = ids[s];
      float4 v = ((const float4*)(W + (size_t)id * D))[t];
      ushort4 o;
      o.x = f2bf(v.x); o.y = f2bf(v.y); o.z = f2bf(v.z); o.w = f2bf(v.w);
      ((ushort4*)(Wg + (size_t)s * D))[t] = o;
    }
  } else {
    const int i = (blockIdx.x - gblocks) * 256 + t;
    float4 v = ((const float4*)x)[i];
    ushort4 o;
    o.x = f2bf(v.x); o.y = f2bf(v.y); o.z = f2bf(v.z); o.w = f2bf(v.w);
    ((ushort4*)xb)[i] = o;
  }
}

__device__ __forceinline__ void load_lds16(const void* g, void* l) {
  __builtin_amdgcn_global_load_lds(
      (const __attribute__((address_space(1))) void*)g,
      (__attribute__((address_space(3))) void*)l, 16, 0, 0);
}

// barrier -> drain own ds_reads -> rule-#18 fence (stop MFMA hoisting)
#define PHASE_OPEN()                                      \
  do {                                                    \
    __builtin_amdgcn_s_barrier();                         \
    asm volatile("s_waitcnt lgkmcnt(0)" ::: "memory");    \
    __builtin_amdgcn_sched_barrier(0);                    \
  } while (0)

// C[M,S] = A[M,K](bf16) * B[S,K](bf16)^T + biasg[S], fp32 out.
__global__ __launch_bounds__(512, 2) void gemm_bt_bias(
    const ushort* __restrict__ A, const ushort* __restrict__ B,
    const float* __restrict__ biasg, float* __restrict__ C,
    int M, int S, int K) {
  // [dbuf(2)][khalf(2)][256 rows][32 cols], phys chunk = logical^((row>>1)&3)
  __shared__ __align__(16) ushort As[4 * HB];
  __shared__ __align__(16) ushort Bs[4 * HB];

  const int tid  = threadIdx.x;
  const int lane = tid & 63;
  const int wave = tid >> 6;
  const int wm = (wave >> 2) * 128;
  const int wn = (wave & 3) * 64;
  const int quad = lane >> 4;
  const int l16  = lane & 15;
  const int bn = blockIdx.x;
  const int bm = blockIdx.y;

  // staging: thread tid, load j -> LDS slot (j*512+tid)*16B within half-buf
  //   row = j*128 + tid/4, phys chunk = tid&3, logical = phys ^ ((row>>1)&3)
  const int srow = tid >> 2;  // + j*128 (swizzle bits unchanged)
  const int scol = (((tid & 3) ^ ((srow >> 1) & 3)) << 3);
  const ushort* Asrc = A + (size_t)(bm * BM + srow) * K + scol;
  const ushort* Bsrc = B + (size_t)(bn * BN + srow) * K + scol;

  // frag reads: row = w*+i*16+l16 -> (row>>1)&3 == (l16>>1)&3 (per-thread const)
  const int rchunk = ((quad ^ ((l16 >> 1) & 3)) << 3);

  f32x4 acc[8][4] = {};

  auto stageA = [&](int hb, int t, int h) {
#pragma unroll
    for (int j = 0; j < 2; ++j)
      load_lds16(Asrc + (size_t)(j * 128) * K + t * BK + h * KH,
                 As + hb * HB + (j * 512 + tid) * 8);
  };
  auto stageB = [&](int hb, int t, int h) {
#pragma unroll
    for (int j = 0; j < 2; ++j)
      load_lds16(Bsrc + (size_t)(j * 128) * K + t * BK + h * KH,
                 Bs + hb * HB + (j * 512 + tid) * 8);
  };
  auto rdA = [&](bf16x8 (&a)[4], int hb, int ibase) {
#pragma unroll
    for (int i = 0; i < 4; ++i)
      a[i] = *(const bf16x8*)(As + hb * HB +
                              (wm + (ibase + i) * 16 + l16) * KH + rchunk);
  };
  auto rdB = [&](bf16x8 (&b)[4], int hb) {
#pragma unroll
    for (int j = 0; j < 4; ++j)
      b[j] = *(const bf16x8*)(Bs + hb * HB + (wn + j * 16 + l16) * KH + rchunk);
  };
  auto mma16 = [&](bf16x8 (&a)[4], bf16x8 (&b)[4], int ibase) {
    __builtin_amdgcn_s_setprio(1);
#pragma unroll
    for (int i = 0; i < 4; ++i)
#pragma unroll
      for (int j = 0; j < 4; ++j)
        acc[ibase + i][j] = __builtin_amdgcn_mfma_f32_16x16x32_bf16(
            a[i], b[j], acc[ibase + i][j], 0, 0, 0);
    __builtin_amdgcn_s_setprio(0);
  };

  // prologue: stage tile 0 in order A0,B0,A1,B1; retire A0,B0; barrier
  stageA(0, 0, 0); stageB(0, 0, 0); stageA(1, 0, 1); stageB(1, 0, 1);
  asm volatile("s_waitcnt vmcnt(4)" ::: "memory");
  __builtin_amdgcn_s_barrier();

  const int NT = K / BK;
  bf16x8 alo[4], ahi[4], bb[4];

  for (int t = 0; t < NT - 1; ++t) {
    const int d  = (t & 1) * 2;
    const int dn = 2 - d;

    // phase 0: k0 | rows 0-3 ; stage A-k0(t+1)
    rdA(alo, d + 0, 0);
    rdB(bb,  d + 0);
    stageA(dn + 0, t + 1, 0);
    PHASE_OPEN();
    mma16(alo, bb, 0);
    __builtin_amdgcn_s_barrier();

    // phase 1: k0 | rows 4-7 ; stage B-k0(t+1); retire A-k1(t),B-k1(t)
    rdA(ahi, d + 0, 4);
    stageB(dn + 0, t + 1, 0);
    PHASE_OPEN();
    mma16(ahi, bb, 4);
    asm volatile("s_waitcnt vmcnt(4)" ::: "memory");
    __builtin_amdgcn_s_barrier();

    // phase 2: k1 | rows 0-3 ; stage A-k1(t+1)
    rdA(alo, d + 1, 0);
    rdB(bb,  d + 1);
    stageA(dn + 1, t + 1, 1);
    PHASE_OPEN();
    mma16(alo, bb, 0);
    __builtin_amdgcn_s_barrier();

    // phase 3: k1 | rows 4-7 ; stage B-k1(t+1); retire A-k0(t+1),B-k0(t+1)
    rdA(ahi, d + 1, 4);
    stageB(dn + 1, t + 1, 1);
    PHASE_OPEN();
    mma16(ahi, bb, 4);
    asm volatile("s_waitcnt vmcnt(4)" ::: "memory");
    __builtin_amdgcn_s_barrier();
  }

  // tail tile (no staging): entry in-flight = [A-k1, B-k1] of this tile
  {
    const int d = ((NT - 1) & 1) * 2;

    rdA(alo, d + 0, 0);
    rdB(bb,  d + 0);
    PHASE_OPEN();
    mma16(alo, bb, 0);
    __builtin_amdgcn_s_barrier();

    rdA(ahi, d + 0, 4);
    PHASE_OPEN();
    mma16(ahi, bb, 4);
    asm volatile("s_waitcnt vmcnt(0)" ::: "memory");
    __builtin_amdgcn_s_barrier();

    rdA(alo, d + 1, 0);
    rdB(bb,  d + 1);
    PHASE_OPEN();
    mma16(alo, bb, 0);
    __builtin_amdgcn_s_barrier();

    rdA(ahi, d + 1, 4);
    PHASE_OPEN();
    mma16(ahi, bb, 4);
  }

  // epilogue: C/D layout col = lane&15, row = quad*4 + reg  [m89/m91]
  const int row0 = bm * BM + wm + quad * 4;
  const int col0 = bn * BN + wn + l16;
#pragma unroll
  for (int jf = 0; jf < 4; ++jf) {
    const int col = col0 + jf * 16;
    const float bv = biasg[col];
#pragma unroll
    for (int i = 0; i < 8; ++i) {
#pragma unroll
      for (int r = 0; r < 4; ++r) {
        C[(size_t)(row0 + i * 16 + r) * S + col] = acc[i][jf][r] + bv;
      }
    }
  }
}

extern "C" void kernel_launch(void* const* d_in, const int* in_sizes, int n_in,
                              void* d_out, int out_size, void* d_ws, size_t ws_size,
                              hipStream_t stream) {
  const float* x    = (const float*)d_in[0];  // [N, D]
  const float* W    = (const float*)d_in[1];  // [OUT, D]
  const float* bias = (const float*)d_in[2];  // [OUT]
  const int*   ids  = (const int*)d_in[3];    // [S]
  float* out = (float*)d_out;                 // [N, S]

  const int OUTN = in_sizes[2];
  const int S    = in_sizes[3];
  const int D    = in_sizes[1] / OUTN;  // 1024
  const int N    = in_sizes[0] / D;     // 2048

  // workspace: Wg bf16 [S,D] | xb bf16 [N,D] | biasg f32 [S]
  ushort* Wg = (ushort*)d_ws;
  ushort* xb = (ushort*)((char*)d_ws + (size_t)S * D * sizeof(ushort));
  float* biasg = (float*)((char*)d_ws + (size_t)S * D * sizeof(ushort)
                          + (size_t)N * D * sizeof(ushort));

  const int gather_blocks = S / 8;
  const int conv_blocks = (N * D) / 1024;
  prep_kernel<<<gather_blocks + conv_blocks, 256, 0, stream>>>(
      x, W, bias, ids, Wg, xb, biasg, D, S);

  dim3 grid(S / BN, N / BM);  // 64 x 8 = 512 blocks
  gemm_bt_bias<<<grid, 512, 0, stream>>>(xb, Wg, biasg, out, N, S, D);
}